// Round 1
// baseline (2703.461 us; speedup 1.0000x reference)
//
#include <hip/hip_runtime.h>
#include <stdint.h>
#include <string.h>

#define DM 256
#define NB 4
#define SEQ 1024
#define NTOK 4096       // NB*SEQ
#define RHID 64
#define DSUM 960        // 64+128+256+512
#define SZ2 348160      // 64^2+128^2+256^2+512^2
#define VOCABN 32000

typedef __attribute__((ext_vector_type(8))) short short8;
typedef __attribute__((ext_vector_type(4))) float floatx4;

__device__ __forceinline__ unsigned short f2bf(float f) {
  unsigned int x = __float_as_uint(f);
  x += 0x7fffu + ((x >> 16) & 1u);
  return (unsigned short)(x >> 16);
}
__device__ __forceinline__ float bf2f(unsigned short u) {
  return __uint_as_float(((unsigned int)u) << 16);
}

struct Ptr4 { const float* p[4]; };

// ---------------- small kernels ----------------

__global__ void k_embed(const int* x, const float* emb, float* xe, unsigned short* xebf) {
  int r = blockIdx.x;            // 0..4095
  int d = threadIdx.x;           // 0..255
  int tok = x[r];
  float v = emb[(size_t)tok * DM + d];
  xe[(size_t)r * DM + d] = v;
  xebf[(size_t)r * DM + d] = f2bf(v);
}

__global__ void k_mean(const float* xe, float* mean) {
  __shared__ float red[4][DM];
  int b = blockIdx.x;
  int tid = threadIdx.x;         // 1024 threads
  int d = tid & 255, tt = tid >> 8;
  float s = 0.f;
  for (int t = tt; t < SEQ; t += 4) s += xe[((size_t)b * SEQ + t) * DM + d];
  red[tt][d] = s;
  __syncthreads();
  if (tt == 0) mean[b * DM + d] = (red[0][d] + red[1][d] + red[2][d] + red[3][d]) * (1.f / SEQ);
}

__global__ void k_router(const float* mean, const float* rw1, const float* rb1,
                         const float* rw2, const float* rb2, Ptr4 Dv,
                         float* wout, float* wD) {
  __shared__ float r1[4][RHID];
  __shared__ float lg[4][4];
  __shared__ float wsh[4][4];
  int tid = threadIdx.x;         // 256
  int b = tid >> 6, h = tid & 63;
  float s = rb1[h];
  for (int d0 = 0; d0 < DM; d0++) s += mean[b * DM + d0] * rw1[d0 * RHID + h];
  r1[b][h] = fmaxf(s, 0.f);
  __syncthreads();
  if (tid < 16) {
    int bb = tid >> 2, i = tid & 3;
    float s2 = rb2[i];
    for (int hh = 0; hh < RHID; hh++) s2 += r1[bb][hh] * rw2[hh * 4 + i];
    lg[bb][i] = s2;
  }
  __syncthreads();
  if (tid < 4) {
    float m = lg[tid][0];
    for (int i = 1; i < 4; i++) m = fmaxf(m, lg[tid][i]);
    float e[4], sum = 0.f;
    for (int i = 0; i < 4; i++) { e[i] = __expf(lg[tid][i] - m); sum += e[i]; }
    for (int i = 0; i < 4; i++) { wsh[tid][i] = e[i] / sum; wout[tid * 4 + i] = wsh[tid][i]; }
  }
  __syncthreads();
  int d = tid;
  for (int bb = 0; bb < 4; bb++) {
    float v = 0.f;
    for (int i = 0; i < 4; i++) v += wsh[bb][i] * Dv.p[i][d];
    wD[bb * DM + d] = v;
  }
}

__device__ __forceinline__ void world_from_id(int id, int& w, int& e) {
  if (id < 4096)        { w = 0; e = id; }
  else if (id < 20480)  { w = 1; e = id - 4096; }
  else if (id < 86016)  { w = 2; e = id - 20480; }
  else                  { w = 3; e = id - 86016; }
}

// M = 0.1*A as hi/lo bf16 + transposed copies
__global__ void k_prep_M(Ptr4 A, unsigned short* Mh, unsigned short* Ml,
                         unsigned short* MTh, unsigned short* MTl) {
  int id = blockIdx.x * 256 + threadIdx.x;   // < SZ2
  int w, e; world_from_id(id, w, e);
  int s = 6 + w, ds = 64 << w;
  int i = e >> s, j = e & (ds - 1);
  float v = 0.1f * A.p[w][e];
  unsigned short h = f2bf(v);
  unsigned short l = f2bf(v - bf2f(h));
  Mh[id] = h; Ml[id] = l;
  int tix = (id - e) + (j << s) + i;
  MTh[tix] = h; MTl[tix] = l;
}

// Ad = I + M + P2/2 + P3/6 + P4/24  -> power slot 0 (hi/lo + transposed hi/lo)
__global__ void k_combine(Ptr4 A, const float* P2f, const float* P3f, const float* P4f,
                          unsigned short* Ph, unsigned short* Pl,
                          unsigned short* PTh, unsigned short* PTl) {
  int id = blockIdx.x * 256 + threadIdx.x;
  int w, e; world_from_id(id, w, e);
  int s = 6 + w, ds = 64 << w;
  int i = e >> s, j = e & (ds - 1);
  float v = ((i == j) ? 1.f : 0.f) + 0.1f * A.p[w][e]
          + 0.5f * P2f[id] + (1.f / 6.f) * P3f[id] + (1.f / 24.f) * P4f[id];
  unsigned short h = f2bf(v);
  unsigned short l = f2bf(v - bf2f(h));
  Ph[id] = h; Pl[id] = l;
  int tix = (id - e) + (j << s) + i;
  PTh[tix] = h; PTl[tix] = l;
}

// BtCat[960][256]: BtCat[off_w + j][d] = B_w[d][j]
__global__ void k_prep_B(Ptr4 B, unsigned short* BtCat) {
  int jc = blockIdx.x;          // 0..959
  int d = threadIdx.x;          // 0..255
  int w, j;
  if (jc < 64)       { w = 0; j = jc; }
  else if (jc < 192) { w = 1; j = jc - 64; }
  else if (jc < 448) { w = 2; j = jc - 192; }
  else               { w = 3; j = jc - 448; }
  int ds = 64 << w;
  BtCat[(size_t)jc * DM + d] = f2bf(B.p[w][(size_t)d * ds + j]);
}

// CtCat[256][960]: CtCat[d][off_w + j] = C_w[j][d]
__global__ void k_prep_C(Ptr4 C, unsigned short* CtCat) {
  int c = blockIdx.x * 256 + threadIdx.x;  // 0..1023
  int d = blockIdx.y;                      // 0..255
  if (c >= DSUM) return;
  int w, j;
  if (c < 64)       { w = 0; j = c; }
  else if (c < 192) { w = 1; j = c - 64; }
  else if (c < 448) { w = 2; j = c - 192; }
  else              { w = 3; j = c - 448; }
  CtCat[(size_t)d * DSUM + c] = f2bf(C.p[w][(size_t)j * DM + d]);
}

// ow [256, 32000] fp32 -> owT [32000, 256] bf16, tiled transpose
__global__ void k_transpose_ow(const float* ow, unsigned short* owT) {
  __shared__ float t[64][65];
  int n0 = blockIdx.x * 64, k0 = blockIdx.y * 64;
  int tid = threadIdx.x;
  int a = tid >> 6, b = tid & 63;
  #pragma unroll
  for (int r = 0; r < 16; r++) {
    int k = r * 4 + a;
    t[k][b] = ow[(size_t)(k0 + k) * VOCABN + n0 + b];
  }
  __syncthreads();
  #pragma unroll
  for (int r = 0; r < 16; r++) {
    int n = r * 4 + a;
    owT[(size_t)(n0 + n) * DM + k0 + b] = f2bf(t[b][n]);
  }
}

// ---------------- universal MFMA GEMM ----------------
// C = A @ B (+ epilogues). A row-major [M x lda] bf16 hi(/lo).
// B supplied TRANSPOSED: Bth/Btl row-major [N x ldbt] = B^T.
// split: 3-product hi/lo emulation (~2^-17 effective precision).
// shift: Kogge-Stone A-row shift with per-1024-row (batch) zero masking.
// ksadd: epilogue += (Ah+Al)[row][col] (unshifted)  -> scan update.

struct GDesc {
  const unsigned short *Ah, *Al, *Bth, *Btl;
  float *Cf;
  unsigned short *Ch, *Cl, *Th, *Tl, *Hc;
  const float *xe, *wD, *bias, *wcol;
  int M, N, K, lda, ldbt, ldc, ldt, shift, split, ksadd, tn, boff;
};
struct GArgs { GDesc d[4]; int nd; };

__global__ __launch_bounds__(256) void gemm_uni(GArgs ga) {
  int di = ga.nd - 1;
  while (di > 0 && (int)blockIdx.x < ga.d[di].boff) di--;
  const GDesc& d = ga.d[di];
  int lb = blockIdx.x - d.boff;
  int tm = lb / d.tn, tnn = lb % d.tn;
  int m0 = tm * 128, n0 = tnn * 128;

  __shared__ unsigned short As[2][128][40];
  __shared__ unsigned short Bs[2][128][40];

  int tid = threadIdx.x;
  int wave = tid >> 6, lane = tid & 63;
  int wm = (wave >> 1) * 64, wn = (wave & 1) * 64;
  int q = lane >> 4, l15 = lane & 15;

  floatx4 acc[4][4];
  #pragma unroll
  for (int i = 0; i < 4; i++)
    #pragma unroll
    for (int j = 0; j < 4; j++)
      acc[i][j] = (floatx4){0.f, 0.f, 0.f, 0.f};

  for (int kt = 0; kt < d.K; kt += 32) {
    __syncthreads();
    #pragma unroll
    for (int c0 = 0; c0 < 2; c0++) {
      int c = c0 * 256 + tid;
      int row = c >> 2, k8 = (c & 3) << 3;
      { // A tile
        int gr = m0 + row;
        bool v = (gr < d.M);
        if (d.shift && ((gr & (SEQ - 1)) < d.shift)) v = false;
        uint4 hv = make_uint4(0, 0, 0, 0), lv = make_uint4(0, 0, 0, 0);
        if (v) {
          size_t idx = (size_t)(gr - d.shift) * d.lda + kt + k8;
          hv = *(const uint4*)(d.Ah + idx);
          if (d.split) lv = *(const uint4*)(d.Al + idx);
        }
        *(uint4*)&As[0][row][k8] = hv;
        if (d.split) *(uint4*)&As[1][row][k8] = lv;
      }
      { // B tile (from B^T)
        int gn = n0 + row;
        uint4 hv = make_uint4(0, 0, 0, 0), lv = make_uint4(0, 0, 0, 0);
        if (gn < d.N) {
          size_t idx = (size_t)gn * d.ldbt + kt + k8;
          hv = *(const uint4*)(d.Bth + idx);
          if (d.split) lv = *(const uint4*)(d.Btl + idx);
        }
        *(uint4*)&Bs[0][row][k8] = hv;
        if (d.split) *(uint4*)&Bs[1][row][k8] = lv;
      }
    }
    __syncthreads();
    short8 bh[4], bl[4];
    #pragma unroll
    for (int j = 0; j < 4; j++)
      bh[j] = *(const short8*)&Bs[0][wn + j * 16 + l15][q * 8];
    if (d.split) {
      #pragma unroll
      for (int j = 0; j < 4; j++)
        bl[j] = *(const short8*)&Bs[1][wn + j * 16 + l15][q * 8];
    }
    #pragma unroll
    for (int i = 0; i < 4; i++) {
      short8 ah = *(const short8*)&As[0][wm + i * 16 + l15][q * 8];
      #pragma unroll
      for (int j = 0; j < 4; j++)
        acc[i][j] = __builtin_amdgcn_mfma_f32_16x16x32_bf16(ah, bh[j], acc[i][j], 0, 0, 0);
      if (d.split) {
        short8 al = *(const short8*)&As[1][wm + i * 16 + l15][q * 8];
        #pragma unroll
        for (int j = 0; j < 4; j++) {
          acc[i][j] = __builtin_amdgcn_mfma_f32_16x16x32_bf16(ah, bl[j], acc[i][j], 0, 0, 0);
          acc[i][j] = __builtin_amdgcn_mfma_f32_16x16x32_bf16(al, bh[j], acc[i][j], 0, 0, 0);
        }
      }
    }
  }

  // epilogue; C/D layout: col = lane&15, row = (lane>>4)*4 + reg  [m89-verified]
  #pragma unroll
  for (int i = 0; i < 4; i++) {
    #pragma unroll
    for (int j = 0; j < 4; j++) {
      int col = n0 + wn + j * 16 + l15;
      if (col >= d.N) continue;
      #pragma unroll
      for (int r = 0; r < 4; r++) {
        int row = m0 + wm + i * 16 + q * 4 + r;
        if (row >= d.M) continue;
        float v = acc[i][j][r];
        size_t ci = (size_t)row * d.ldc + col;
        if (d.ksadd) {
          size_t ai = (size_t)row * d.lda + col;
          v += bf2f(d.Ah[ai]) + bf2f(d.Al[ai]);
        }
        if (d.xe) v += d.xe[(size_t)row * DM + col] * d.wD[(size_t)(row >> 10) * DM + col];
        if (d.bias) v += d.bias[col];
        if (d.Cf) d.Cf[ci] = v;
        if (d.Ch) {
          unsigned short h = f2bf(v);
          d.Ch[ci] = h;
          if (d.Cl) d.Cl[ci] = f2bf(v - bf2f(h));
        }
        if (d.Th) {
          size_t tix = (size_t)col * d.ldt + row;
          unsigned short h = f2bf(v);
          d.Th[tix] = h;
          d.Tl[tix] = f2bf(v - bf2f(h));
        }
        if (d.Hc) d.Hc[(size_t)row * DSUM + col] = f2bf(v * d.wcol[(size_t)(row >> 10) * 4]);
      }
    }
  }
}

// ---------------- host ----------------

extern "C" void kernel_launch(void* const* d_in, const int* in_sizes, int n_in,
                              void* d_out, int out_size, void* d_ws, size_t ws_size,
                              hipStream_t stream) {
  const int*   x   = (const int*)d_in[0];
  const float* emb = (const float*)d_in[1];
  Ptr4 Aw = {{(const float*)d_in[2], (const float*)d_in[6], (const float*)d_in[10], (const float*)d_in[14]}};
  Ptr4 Bw = {{(const float*)d_in[3], (const float*)d_in[7], (const float*)d_in[11], (const float*)d_in[15]}};
  Ptr4 Cw = {{(const float*)d_in[4], (const float*)d_in[8], (const float*)d_in[12], (const float*)d_in[16]}};
  Ptr4 Dw = {{(const float*)d_in[5], (const float*)d_in[9], (const float*)d_in[13], (const float*)d_in[17]}};
  const float* rw1 = (const float*)d_in[18];
  const float* rb1 = (const float*)d_in[19];
  const float* rw2 = (const float*)d_in[20];
  const float* rb2 = (const float*)d_in[21];
  const float* ow  = (const float*)d_in[22];
  const float* ob  = (const float*)d_in[23];
  float* out = (float*)d_out;

  char* wsb = (char*)d_ws;
  size_t off = 0;
  auto alloc = [&](size_t bytes) { size_t o = off; off = (off + bytes + 255) & ~(size_t)255; return o; };

  size_t o_xef  = alloc((size_t)NTOK * DM * 4);
  size_t o_xebf = alloc((size_t)NTOK * DM * 2);
  size_t o_mean = alloc(4 * DM * 4);
  size_t o_w    = alloc(64);
  size_t o_wD   = alloc(4 * DM * 4);
  size_t o_Mh   = alloc((size_t)SZ2 * 2), o_Ml = alloc((size_t)SZ2 * 2);
  size_t o_MTh  = alloc((size_t)SZ2 * 2), o_MTl = alloc((size_t)SZ2 * 2);
  size_t o_P2f  = alloc((size_t)SZ2 * 4);
  size_t o_P2h  = alloc((size_t)SZ2 * 2), o_P2l = alloc((size_t)SZ2 * 2);
  size_t o_P2Th = alloc((size_t)SZ2 * 2), o_P2Tl = alloc((size_t)SZ2 * 2);
  size_t o_P3f  = alloc((size_t)SZ2 * 4);
  size_t o_P4f  = alloc((size_t)SZ2 * 4);
  size_t o_Ph   = alloc((size_t)10 * SZ2 * 2), o_Pl  = alloc((size_t)10 * SZ2 * 2);
  size_t o_PTh  = alloc((size_t)10 * SZ2 * 2), o_PTl = alloc((size_t)10 * SZ2 * 2);
  size_t o_Xah  = alloc((size_t)NTOK * DSUM * 2), o_Xal = alloc((size_t)NTOK * DSUM * 2);
  size_t o_Xbh  = alloc((size_t)NTOK * DSUM * 2), o_Xbl = alloc((size_t)NTOK * DSUM * 2);
  size_t o_Hc   = alloc((size_t)NTOK * DSUM * 2);
  size_t o_op   = alloc((size_t)NTOK * DM * 2);
  size_t o_Bt   = alloc((size_t)DSUM * DM * 2);
  size_t o_Ct   = alloc((size_t)DM * DSUM * 2);
  size_t o_owT  = alloc((size_t)VOCABN * DM * 2);

  auto U16 = [&](size_t o) { return (unsigned short*)(wsb + o); };
  auto F32 = [&](size_t o) { return (float*)(wsb + o); };

  const int dsw[4] = {64, 128, 256, 512};
  const size_t off2[4] = {0, 4096, 20480, 86016};
  const int offc[4] = {0, 64, 192, 448};

  auto launch = [&](GArgs& a) {
    int total = 0;
    for (int i = 0; i < a.nd; i++) {
      a.d[i].boff = total;
      int tm = (a.d[i].M + 127) / 128, tn = (a.d[i].N + 127) / 128;
      a.d[i].tn = tn;
      total += tm * tn;
    }
    gemm_uni<<<total, 256, 0, stream>>>(a);
  };
  auto zd = []() { GDesc d; memset(&d, 0, sizeof(d)); return d; };

  // 1. embed + bf16 copy
  k_embed<<<NTOK, DM, 0, stream>>>(x, emb, F32(o_xef), U16(o_xebf));
  // 2. mean
  k_mean<<<NB, 1024, 0, stream>>>(F32(o_xef), F32(o_mean));
  // 3. router -> w, wD
  k_router<<<1, 256, 0, stream>>>(F32(o_mean), rw1, rb1, rw2, rb2, Dw, F32(o_w), F32(o_wD));
  // 4. prep M (hi/lo + T)
  k_prep_M<<<SZ2 / 256, 256, 0, stream>>>(Aw, U16(o_Mh), U16(o_Ml), U16(o_MTh), U16(o_MTl));
  // 5. prep B^T cat, C^T cat, ow^T
  k_prep_B<<<DSUM, 256, 0, stream>>>(Bw, U16(o_Bt));
  k_prep_C<<<dim3(4, 256), 256, 0, stream>>>(Cw, U16(o_Ct));
  k_transpose_ow<<<dim3(VOCABN / 64, DM / 64), 256, 0, stream>>>(ow, U16(o_owT));

  // 6. expm Taylor: P2 = M@M ; P3 = P2@M ; P4 = P2@P2
  {
    GArgs a; a.nd = 4;
    for (int w = 0; w < 4; w++) {
      GDesc d = zd();
      d.Ah = U16(o_Mh) + off2[w]; d.Al = U16(o_Ml) + off2[w];
      d.Bth = U16(o_MTh) + off2[w]; d.Btl = U16(o_MTl) + off2[w];
      d.Cf = F32(o_P2f) + off2[w];
      d.Ch = U16(o_P2h) + off2[w]; d.Cl = U16(o_P2l) + off2[w];
      d.Th = U16(o_P2Th) + off2[w]; d.Tl = U16(o_P2Tl) + off2[w];
      d.M = d.N = d.K = d.lda = d.ldbt = d.ldc = d.ldt = dsw[w];
      d.split = 1;
      a.d[w] = d;
    }
    launch(a);
  }
  {
    GArgs a; a.nd = 4;
    for (int w = 0; w < 4; w++) {
      GDesc d = zd();
      d.Ah = U16(o_P2h) + off2[w]; d.Al = U16(o_P2l) + off2[w];
      d.Bth = U16(o_MTh) + off2[w]; d.Btl = U16(o_MTl) + off2[w];
      d.Cf = F32(o_P3f) + off2[w];
      d.M = d.N = d.K = d.lda = d.ldbt = d.ldc = dsw[w];
      d.split = 1;
      a.d[w] = d;
    }
    launch(a);
  }
  {
    GArgs a; a.nd = 4;
    for (int w = 0; w < 4; w++) {
      GDesc d = zd();
      d.Ah = U16(o_P2h) + off2[w]; d.Al = U16(o_P2l) + off2[w];
      d.Bth = U16(o_P2Th) + off2[w]; d.Btl = U16(o_P2Tl) + off2[w];
      d.Cf = F32(o_P4f) + off2[w];
      d.M = d.N = d.K = d.lda = d.ldbt = d.ldc = dsw[w];
      d.split = 1;
      a.d[w] = d;
    }
    launch(a);
  }
  // 7. combine -> power slot 0 (Ad)
  k_combine<<<SZ2 / 256, 256, 0, stream>>>(Aw, F32(o_P2f), F32(o_P3f), F32(o_P4f),
                                           U16(o_Ph), U16(o_Pl), U16(o_PTh), U16(o_PTl));
  // 8. squaring chain: slots 1..9, P_j = P_{j-1}^2
  for (int j = 1; j < 10; j++) {
    GArgs a; a.nd = 4;
    for (int w = 0; w < 4; w++) {
      size_t so = (size_t)(j - 1) * SZ2 + off2[w];
      size_t do_ = (size_t)j * SZ2 + off2[w];
      GDesc d = zd();
      d.Ah = U16(o_Ph) + so; d.Al = U16(o_Pl) + so;
      d.Bth = U16(o_PTh) + so; d.Btl = U16(o_PTl) + so;
      d.Ch = U16(o_Ph) + do_; d.Cl = U16(o_Pl) + do_;
      d.Th = U16(o_PTh) + do_; d.Tl = U16(o_PTl) + do_;
      d.M = d.N = d.K = d.lda = d.ldbt = d.ldc = d.ldt = dsw[w];
      d.split = 1;
      a.d[w] = d;
    }
    launch(a);
  }
  // 9. U = xe @ B_w  -> X_a (hi/lo)
  {
    GArgs a; a.nd = 4;
    for (int w = 0; w < 4; w++) {
      GDesc d = zd();
      d.Ah = U16(o_xebf);
      d.Bth = U16(o_Bt) + (size_t)offc[w] * DM;
      d.Ch = U16(o_Xah) + (size_t)NTOK * offc[w];
      d.Cl = U16(o_Xal) + (size_t)NTOK * offc[w];
      d.M = NTOK; d.N = dsw[w]; d.K = DM;
      d.lda = DM; d.ldbt = DM; d.ldc = dsw[w];
      a.d[w] = d;
    }
    launch(a);
  }
  // 10. Kogge-Stone scan: 10 rounds, X[t] += X[t-2^j] @ Ad^{2^j}
  size_t xin_h = o_Xah, xin_l = o_Xal, xout_h = o_Xbh, xout_l = o_Xbl;
  for (int j = 0; j < 10; j++) {
    GArgs a; a.nd = 4;
    for (int w = 0; w < 4; w++) {
      GDesc d = zd();
      d.Ah = U16(xin_h) + (size_t)NTOK * offc[w];
      d.Al = U16(xin_l) + (size_t)NTOK * offc[w];
      d.Bth = U16(o_PTh) + (size_t)j * SZ2 + off2[w];
      d.Btl = U16(o_PTl) + (size_t)j * SZ2 + off2[w];
      d.Ch = U16(xout_h) + (size_t)NTOK * offc[w];
      d.Cl = U16(xout_l) + (size_t)NTOK * offc[w];
      d.M = NTOK; d.N = dsw[w]; d.K = dsw[w];
      d.lda = dsw[w]; d.ldbt = dsw[w]; d.ldc = dsw[w];
      d.shift = 1 << j; d.split = 1; d.ksadd = 1;
      if (j == 9) {                       // final round: also emit w-scaled H_cat
        d.Hc = U16(o_Hc) + offc[w];
        d.wcol = F32(o_w) + w;
      }
      a.d[w] = d;
    }
    launch(a);
    size_t th = xin_h, tl = xin_l;
    xin_h = xout_h; xin_l = xout_l; xout_h = th; xout_l = tl;
  }
  // 11. out_pre = H_cat @ C_cat + xe*wD   (bf16 out)
  {
    GArgs a; a.nd = 1;
    GDesc d = zd();
    d.Ah = U16(o_Hc); d.Bth = U16(o_Ct);
    d.M = NTOK; d.N = DM; d.K = DSUM;
    d.lda = DSUM; d.ldbt = DSUM; d.ldc = DM;
    d.xe = F32(o_xef); d.wD = F32(o_wD);
    d.Ch = U16(o_op);
    a.d[0] = d;
    launch(a);
  }
  // 12. out = out_pre @ ow + ob   (fp32 out)
  {
    GArgs a; a.nd = 1;
    GDesc d = zd();
    d.Ah = U16(o_op); d.Bth = U16(o_owT);
    d.M = NTOK; d.N = VOCABN; d.K = DM;
    d.lda = DM; d.ldbt = DM; d.ldc = VOCABN;
    d.Cf = out; d.bias = ob;
    a.d[0] = d;
    launch(a);
  }
  (void)in_sizes; (void)n_in; (void)out_size; (void)ws_size;
}

// Round 2
// 1975.968 us; speedup vs baseline: 1.3682x; 1.3682x over previous
//
#include <hip/hip_runtime.h>
#include <stdint.h>
#include <string.h>

#define DM 256
#define NB 4
#define SEQ 1024
#define NTOK 4096       // NB*SEQ
#define RHID 64
#define DSUM 960        // 64+128+256+512
#define SZ2 348160      // 64^2+128^2+256^2+512^2
#define VOCABN 32000
#define XROWS 6144      // 4 batches * (512 pad + 1024 data)
#define XPADE (XROWS * DSUM)   // elements per padded X array

typedef __attribute__((ext_vector_type(8))) short short8;
typedef __attribute__((ext_vector_type(4))) float floatx4;

__device__ __forceinline__ unsigned short f2bf(float f) {
  unsigned int x = __float_as_uint(f);
  x += 0x7fffu + ((x >> 16) & 1u);
  return (unsigned short)(x >> 16);
}
__device__ __forceinline__ float bf2f(unsigned short u) {
  return __uint_as_float(((unsigned int)u) << 16);
}

// async global->LDS, 16B per lane; lds base must be wave-uniform, lane i lands at base + i*16B
__device__ __forceinline__ void gll16(const unsigned short* g, unsigned short* l) {
  __builtin_amdgcn_global_load_lds((const __attribute__((address_space(1))) void*)g,
                                   (__attribute__((address_space(3))) void*)l, 16, 0, 0);
}

struct Ptr4 { const float* p[4]; };

// ---------------- small kernels ----------------

__global__ void k_embed(const int* x, const float* emb, float* xe, unsigned short* xebf) {
  int r = blockIdx.x;
  int d = threadIdx.x;
  int tok = x[r];
  float v = emb[(size_t)tok * DM + d];
  xe[(size_t)r * DM + d] = v;
  xebf[(size_t)r * DM + d] = f2bf(v);
}

__global__ void k_mean(const float* xe, float* mean) {
  __shared__ float red[4][DM];
  int b = blockIdx.x;
  int tid = threadIdx.x;
  int d = tid & 255, tt = tid >> 8;
  float s = 0.f;
  for (int t = tt; t < SEQ; t += 4) s += xe[((size_t)b * SEQ + t) * DM + d];
  red[tt][d] = s;
  __syncthreads();
  if (tt == 0) mean[b * DM + d] = (red[0][d] + red[1][d] + red[2][d] + red[3][d]) * (1.f / SEQ);
}

__global__ void k_router(const float* mean, const float* rw1, const float* rb1,
                         const float* rw2, const float* rb2, Ptr4 Dv,
                         float* wout, float* wD) {
  __shared__ float r1[4][RHID];
  __shared__ float lg[4][4];
  __shared__ float wsh[4][4];
  int tid = threadIdx.x;
  int b = tid >> 6, h = tid & 63;
  float s = rb1[h];
  for (int d0 = 0; d0 < DM; d0++) s += mean[b * DM + d0] * rw1[d0 * RHID + h];
  r1[b][h] = fmaxf(s, 0.f);
  __syncthreads();
  if (tid < 16) {
    int bb = tid >> 2, i = tid & 3;
    float s2 = rb2[i];
    for (int hh = 0; hh < RHID; hh++) s2 += r1[bb][hh] * rw2[hh * 4 + i];
    lg[bb][i] = s2;
  }
  __syncthreads();
  if (tid < 4) {
    float m = lg[tid][0];
    for (int i = 1; i < 4; i++) m = fmaxf(m, lg[tid][i]);
    float e[4], sum = 0.f;
    for (int i = 0; i < 4; i++) { e[i] = __expf(lg[tid][i] - m); sum += e[i]; }
    for (int i = 0; i < 4; i++) { wsh[tid][i] = e[i] / sum; wout[tid * 4 + i] = wsh[tid][i]; }
  }
  __syncthreads();
  int d = tid;
  for (int bb = 0; bb < 4; bb++) {
    float v = 0.f;
    for (int i = 0; i < 4; i++) v += wsh[bb][i] * Dv.p[i][d];
    wD[bb * DM + d] = v;
  }
}

__device__ __forceinline__ void world_from_id(int id, int& w, int& e) {
  if (id < 4096)        { w = 0; e = id; }
  else if (id < 20480)  { w = 1; e = id - 4096; }
  else if (id < 86016)  { w = 2; e = id - 20480; }
  else                  { w = 3; e = id - 86016; }
}

__global__ void k_prep_M(Ptr4 A, unsigned short* Mh, unsigned short* Ml,
                         unsigned short* MTh, unsigned short* MTl) {
  int id = blockIdx.x * 256 + threadIdx.x;
  int w, e; world_from_id(id, w, e);
  int s = 6 + w, ds = 64 << w;
  int i = e >> s, j = e & (ds - 1);
  float v = 0.1f * A.p[w][e];
  unsigned short h = f2bf(v);
  unsigned short l = f2bf(v - bf2f(h));
  Mh[id] = h; Ml[id] = l;
  int tix = (id - e) + (j << s) + i;
  MTh[tix] = h; MTl[tix] = l;
}

__global__ void k_combine(Ptr4 A, const float* P2f, const float* P3f, const float* P4f,
                          unsigned short* Ph, unsigned short* Pl,
                          unsigned short* PTh, unsigned short* PTl) {
  int id = blockIdx.x * 256 + threadIdx.x;
  int w, e; world_from_id(id, w, e);
  int s = 6 + w, ds = 64 << w;
  int i = e >> s, j = e & (ds - 1);
  float v = ((i == j) ? 1.f : 0.f) + 0.1f * A.p[w][e]
          + 0.5f * P2f[id] + (1.f / 6.f) * P3f[id] + (1.f / 24.f) * P4f[id];
  unsigned short h = f2bf(v);
  unsigned short l = f2bf(v - bf2f(h));
  Ph[id] = h; Pl[id] = l;
  int tix = (id - e) + (j << s) + i;
  PTh[tix] = h; PTl[tix] = l;
}

__global__ void k_prep_B(Ptr4 B, unsigned short* BtCat) {
  int jc = blockIdx.x;
  int d = threadIdx.x;
  int w, j;
  if (jc < 64)       { w = 0; j = jc; }
  else if (jc < 192) { w = 1; j = jc - 64; }
  else if (jc < 448) { w = 2; j = jc - 192; }
  else               { w = 3; j = jc - 448; }
  int ds = 64 << w;
  BtCat[(size_t)jc * DM + d] = f2bf(B.p[w][(size_t)d * ds + j]);
}

__global__ void k_prep_C(Ptr4 C, unsigned short* CtCat) {
  int c = blockIdx.x * 256 + threadIdx.x;
  int d = blockIdx.y;
  if (c >= DSUM) return;
  int w, j;
  if (c < 64)       { w = 0; j = c; }
  else if (c < 192) { w = 1; j = c - 64; }
  else if (c < 448) { w = 2; j = c - 192; }
  else              { w = 3; j = c - 448; }
  CtCat[(size_t)d * DSUM + c] = f2bf(C.p[w][(size_t)j * DM + d]);
}

__global__ void k_transpose_ow(const float* ow, unsigned short* owT) {
  __shared__ float t[64][65];
  int n0 = blockIdx.x * 64, k0 = blockIdx.y * 64;
  int tid = threadIdx.x;
  int a = tid >> 6, b = tid & 63;
  #pragma unroll
  for (int r = 0; r < 16; r++) {
    int k = r * 4 + a;
    t[k][b] = ow[(size_t)(k0 + k) * VOCABN + n0 + b];
  }
  __syncthreads();
  #pragma unroll
  for (int r = 0; r < 16; r++) {
    int n = r * 4 + a;
    owT[(size_t)(n0 + n) * DM + k0 + b] = f2bf(t[b][n]);
  }
}

__global__ void k_zero(uint4* p, long n) {
  long i = (long)blockIdx.x * blockDim.x + threadIdx.x;
  long stride = (long)gridDim.x * blockDim.x;
  uint4 z = make_uint4(0, 0, 0, 0);
  for (; i < n; i += stride) p[i] = z;
}

__global__ void k_finish_op(const float* opf, const float* xe, const float* wD, unsigned short* op) {
  int r = blockIdx.x, dcol = threadIdx.x;
  size_t i = (size_t)r * DM + dcol;
  op[i] = f2bf(opf[i] + xe[i] * wD[(size_t)(r >> 10) * DM + dcol]);
}

// ---------------- old universal GEMM (kept for expm + squaring chain only) ----------------

struct GDesc {
  const unsigned short *Ah, *Al, *Bth, *Btl;
  float *Cf;
  unsigned short *Ch, *Cl, *Th, *Tl;
  int M, N, K, lda, ldbt, ldc, ldt, split, tn, boff;
};
struct GArgs { GDesc d[4]; int nd; };

__global__ __launch_bounds__(256) void gemm_uni(GArgs ga) {
  int di = ga.nd - 1;
  while (di > 0 && (int)blockIdx.x < ga.d[di].boff) di--;
  const GDesc& d = ga.d[di];
  int lb = blockIdx.x - d.boff;
  int tm = lb / d.tn, tnn = lb % d.tn;
  int m0 = tm * 128, n0 = tnn * 128;

  __shared__ unsigned short As[2][128][40];
  __shared__ unsigned short Bs[2][128][40];

  int tid = threadIdx.x;
  int wave = tid >> 6, lane = tid & 63;
  int wm = (wave >> 1) * 64, wn = (wave & 1) * 64;
  int q = lane >> 4, l15 = lane & 15;

  floatx4 acc[4][4];
  #pragma unroll
  for (int i = 0; i < 4; i++)
    #pragma unroll
    for (int j = 0; j < 4; j++)
      acc[i][j] = (floatx4){0.f, 0.f, 0.f, 0.f};

  for (int kt = 0; kt < d.K; kt += 32) {
    __syncthreads();
    #pragma unroll
    for (int c0 = 0; c0 < 2; c0++) {
      int c = c0 * 256 + tid;
      int row = c >> 2, k8 = (c & 3) << 3;
      {
        int gr = m0 + row;
        uint4 hv = make_uint4(0, 0, 0, 0), lv = make_uint4(0, 0, 0, 0);
        if (gr < d.M) {
          size_t idx = (size_t)gr * d.lda + kt + k8;
          hv = *(const uint4*)(d.Ah + idx);
          if (d.split) lv = *(const uint4*)(d.Al + idx);
        }
        *(uint4*)&As[0][row][k8] = hv;
        if (d.split) *(uint4*)&As[1][row][k8] = lv;
      }
      {
        int gn = n0 + row;
        uint4 hv = make_uint4(0, 0, 0, 0), lv = make_uint4(0, 0, 0, 0);
        if (gn < d.N) {
          size_t idx = (size_t)gn * d.ldbt + kt + k8;
          hv = *(const uint4*)(d.Bth + idx);
          if (d.split) lv = *(const uint4*)(d.Btl + idx);
        }
        *(uint4*)&Bs[0][row][k8] = hv;
        if (d.split) *(uint4*)&Bs[1][row][k8] = lv;
      }
    }
    __syncthreads();
    short8 bh[4], bl[4];
    #pragma unroll
    for (int j = 0; j < 4; j++)
      bh[j] = *(const short8*)&Bs[0][wn + j * 16 + l15][q * 8];
    if (d.split) {
      #pragma unroll
      for (int j = 0; j < 4; j++)
        bl[j] = *(const short8*)&Bs[1][wn + j * 16 + l15][q * 8];
    }
    #pragma unroll
    for (int i = 0; i < 4; i++) {
      short8 ah = *(const short8*)&As[0][wm + i * 16 + l15][q * 8];
      #pragma unroll
      for (int j = 0; j < 4; j++)
        acc[i][j] = __builtin_amdgcn_mfma_f32_16x16x32_bf16(ah, bh[j], acc[i][j], 0, 0, 0);
      if (d.split) {
        short8 al = *(const short8*)&As[1][wm + i * 16 + l15][q * 8];
        #pragma unroll
        for (int j = 0; j < 4; j++) {
          acc[i][j] = __builtin_amdgcn_mfma_f32_16x16x32_bf16(ah, bl[j], acc[i][j], 0, 0, 0);
          acc[i][j] = __builtin_amdgcn_mfma_f32_16x16x32_bf16(al, bh[j], acc[i][j], 0, 0, 0);
        }
      }
    }
  }

  #pragma unroll
  for (int i = 0; i < 4; i++) {
    #pragma unroll
    for (int j = 0; j < 4; j++) {
      int col = n0 + wn + j * 16 + l15;
      if (col >= d.N) continue;
      #pragma unroll
      for (int r = 0; r < 4; r++) {
        int row = m0 + wm + i * 16 + q * 4 + r;
        if (row >= d.M) continue;
        float v = acc[i][j][r];
        size_t ci = (size_t)row * d.ldc + col;
        if (d.Cf) d.Cf[ci] = v;
        if (d.Ch) {
          unsigned short h = f2bf(v);
          d.Ch[ci] = h;
          if (d.Cl) d.Cl[ci] = f2bf(v - bf2f(h));
        }
        if (d.Th) {
          size_t tix = (size_t)col * d.ldt + row;
          unsigned short h = f2bf(v);
          d.Th[tix] = h;
          d.Tl[tix] = f2bf(v - bf2f(h));
        }
      }
    }
  }
}

// ---------------- fast MFMA GEMM: KS rounds + U projection ----------------
// m97 structure: unpadded LDS [128][32], global_load_lds width-16 staging.
// X lives in a zero-padded layout: per batch, 512 zero rows then 1024 data rows
// (padrow(t) = (t>>10)*1536 + 512 + (t&1023)), so shifted reads never need masks.

struct KDesc {
  const unsigned short *Ah, *Al, *Bth, *Btl;
  unsigned short *Ch, *Cl, *Hc;
  const float* wcol;
  int N, K, lda, ldbt, shift, hcoff, tn, boff;
};
struct KArgs { KDesc d[4]; int nd; };

template<int SPLIT, int KS>
__global__ __launch_bounds__(256) void gemm_x(KArgs ga) {
  int di = ga.nd - 1;
  while (di > 0 && (int)blockIdx.x < ga.d[di].boff) di--;
  const KDesc& d = ga.d[di];
  int lb = blockIdx.x - d.boff;
  int tm = lb / d.tn, tnn = lb % d.tn;
  int m0 = tm * 128, n0 = tnn * 128;
  int prow0 = ((m0 >> 10) * 1536) + 512 + (m0 & 1023);   // padded out-row base
  int arow0 = KS ? (prow0 - d.shift) : m0;               // staging row base

  __shared__ unsigned short As[(SPLIT ? 2 : 1) * 4096];
  __shared__ unsigned short Bs[(SPLIT ? 2 : 1) * 4096];

  int tid = threadIdx.x;
  int wave = tid >> 6, lane = tid & 63;
  int wm = (wave >> 1) * 64, wn = (wave & 1) * 64;
  int q = lane >> 4, l15 = lane & 15;
  int srow = lane >> 2, scol = (lane & 3) * 8;

  floatx4 acc[4][4];
  #pragma unroll
  for (int i = 0; i < 4; i++)
    #pragma unroll
    for (int j = 0; j < 4; j++)
      acc[i][j] = (floatx4){0.f, 0.f, 0.f, 0.f};

  for (int kt = 0; kt < d.K; kt += 32) {
    // stage: wave handles 32 A-rows + 32 B-rows, 2 instrs each (16 rows/instr)
    int ar = arow0 + wave * 32 + srow;
    int br = n0 + wave * 32 + srow;
    const unsigned short* ag = d.Ah + (size_t)ar * d.lda + kt + scol;
    const unsigned short* bg = d.Bth + (size_t)br * d.ldbt + kt + scol;
    size_t as16 = (size_t)16 * d.lda, bs16 = (size_t)16 * d.ldbt;
    unsigned short* al0 = &As[wave * 32 * 32];
    unsigned short* bl0 = &Bs[wave * 32 * 32];
    gll16(ag, al0);        gll16(ag + as16, al0 + 512);
    gll16(bg, bl0);        gll16(bg + bs16, bl0 + 512);
    if (SPLIT) {
      const unsigned short* ag2 = d.Al + (size_t)ar * d.lda + kt + scol;
      const unsigned short* bg2 = d.Btl + (size_t)br * d.ldbt + kt + scol;
      gll16(ag2, al0 + 4096); gll16(ag2 + as16, al0 + 4096 + 512);
      gll16(bg2, bl0 + 4096); gll16(bg2 + bs16, bl0 + 4096 + 512);
    }
    __syncthreads();
    short8 bh[4], bl[4];
    #pragma unroll
    for (int j = 0; j < 4; j++)
      bh[j] = *(const short8*)&Bs[(wn + j * 16 + l15) * 32 + q * 8];
    if (SPLIT) {
      #pragma unroll
      for (int j = 0; j < 4; j++)
        bl[j] = *(const short8*)&Bs[4096 + (wn + j * 16 + l15) * 32 + q * 8];
    }
    #pragma unroll
    for (int i = 0; i < 4; i++) {
      short8 ah = *(const short8*)&As[(wm + i * 16 + l15) * 32 + q * 8];
      #pragma unroll
      for (int j = 0; j < 4; j++)
        acc[i][j] = __builtin_amdgcn_mfma_f32_16x16x32_bf16(ah, bh[j], acc[i][j], 0, 0, 0);
      if (SPLIT) {
        short8 al = *(const short8*)&As[4096 + (wm + i * 16 + l15) * 32 + q * 8];
        #pragma unroll
        for (int j = 0; j < 4; j++) {
          acc[i][j] = __builtin_amdgcn_mfma_f32_16x16x32_bf16(ah, bl[j], acc[i][j], 0, 0, 0);
          acc[i][j] = __builtin_amdgcn_mfma_f32_16x16x32_bf16(al, bh[j], acc[i][j], 0, 0, 0);
        }
      }
    }
    __syncthreads();
  }

  #pragma unroll
  for (int j = 0; j < 4; j++) {
    int col = n0 + wn + j * 16 + l15;
    if (col >= d.N) continue;
    #pragma unroll
    for (int i = 0; i < 4; i++) {
      #pragma unroll
      for (int r = 0; r < 4; r++) {
        int rr = wm + i * 16 + q * 4 + r;
        size_t oi = (size_t)(prow0 + rr) * d.N + col;
        float v = acc[i][j][r];
        if (KS) v += bf2f(d.Ah[oi]) + bf2f(d.Al[oi]);
        unsigned short h = f2bf(v);
        d.Ch[oi] = h;
        d.Cl[oi] = f2bf(v - bf2f(h));
        if (KS && d.Hc) {
          int grow = m0 + rr;
          d.Hc[(size_t)grow * DSUM + d.hcoff + col] = f2bf(v * d.wcol[(m0 >> 10) * 4]);
        }
      }
    }
  }
}

// ---------------- step 11: H_cat @ C_cat, split-K x5, fp32 atomic accumulate ----------------

__global__ __launch_bounds__(256) void gemm_cct(const unsigned short* __restrict__ Hc,
                                                const unsigned short* __restrict__ Ct,
                                                float* __restrict__ opf) {
  int bx = blockIdx.x;                  // 320 = 5 chunks * 32 tm * 2 tn
  int chunk = bx / 64, lb = bx % 64;
  int tm = lb >> 1, tnn = lb & 1;
  int m0 = tm * 128, n0 = tnn * 128;
  int kt0 = chunk * 192;

  __shared__ unsigned short As[4096], Bs[4096];
  int tid = threadIdx.x;
  int wave = tid >> 6, lane = tid & 63;
  int wm = (wave >> 1) * 64, wn = (wave & 1) * 64;
  int q = lane >> 4, l15 = lane & 15;
  int srow = lane >> 2, scol = (lane & 3) * 8;

  floatx4 acc[4][4];
  #pragma unroll
  for (int i = 0; i < 4; i++)
    #pragma unroll
    for (int j = 0; j < 4; j++)
      acc[i][j] = (floatx4){0.f, 0.f, 0.f, 0.f};

  for (int k = 0; k < 192; k += 32) {
    int kt = kt0 + k;
    const unsigned short* ag = Hc + (size_t)(m0 + wave * 32 + srow) * DSUM + kt + scol;
    const unsigned short* bg = Ct + (size_t)(n0 + wave * 32 + srow) * DSUM + kt + scol;
    unsigned short* al0 = &As[wave * 32 * 32];
    unsigned short* bl0 = &Bs[wave * 32 * 32];
    gll16(ag, al0); gll16(ag + 16 * DSUM, al0 + 512);
    gll16(bg, bl0); gll16(bg + 16 * DSUM, bl0 + 512);
    __syncthreads();
    short8 bh[4];
    #pragma unroll
    for (int j = 0; j < 4; j++)
      bh[j] = *(const short8*)&Bs[(wn + j * 16 + l15) * 32 + q * 8];
    #pragma unroll
    for (int i = 0; i < 4; i++) {
      short8 ah = *(const short8*)&As[(wm + i * 16 + l15) * 32 + q * 8];
      #pragma unroll
      for (int j = 0; j < 4; j++)
        acc[i][j] = __builtin_amdgcn_mfma_f32_16x16x32_bf16(ah, bh[j], acc[i][j], 0, 0, 0);
    }
    __syncthreads();
  }

  #pragma unroll
  for (int j = 0; j < 4; j++) {
    int col = n0 + wn + j * 16 + l15;
    #pragma unroll
    for (int i = 0; i < 4; i++) {
      #pragma unroll
      for (int r = 0; r < 4; r++) {
        int row = m0 + wm + i * 16 + q * 4 + r;
        atomicAdd(&opf[(size_t)row * DM + col], acc[i][j][r]);
      }
    }
  }
}

// ---------------- step 12: final projection [4096,256]@[256,32000] + bias, fp32 out ----------------

__global__ __launch_bounds__(256) void gemm_big(const unsigned short* __restrict__ A,
                                                const unsigned short* __restrict__ B,
                                                const float* __restrict__ bias,
                                                float* __restrict__ out) {
  int bx = blockIdx.x;                  // 8000; m-fastest so 32-consecutive share the B tile
  int tm = bx & 31, tn = bx >> 5;
  int m0 = tm * 128, n0 = tn * 128;

  __shared__ unsigned short As[4096], Bs[4096];
  int tid = threadIdx.x;
  int wave = tid >> 6, lane = tid & 63;
  int wm = (wave >> 1) * 64, wn = (wave & 1) * 64;
  int q = lane >> 4, l15 = lane & 15;
  int srow = lane >> 2, scol = (lane & 3) * 8;

  floatx4 acc[4][4];
  #pragma unroll
  for (int i = 0; i < 4; i++)
    #pragma unroll
    for (int j = 0; j < 4; j++)
      acc[i][j] = (floatx4){0.f, 0.f, 0.f, 0.f};

  for (int kt = 0; kt < DM; kt += 32) {
    const unsigned short* ag = A + (size_t)(m0 + wave * 32 + srow) * DM + kt + scol;
    const unsigned short* bg = B + (size_t)(n0 + wave * 32 + srow) * DM + kt + scol;
    unsigned short* al0 = &As[wave * 32 * 32];
    unsigned short* bl0 = &Bs[wave * 32 * 32];
    gll16(ag, al0); gll16(ag + 16 * DM, al0 + 512);
    gll16(bg, bl0); gll16(bg + 16 * DM, bl0 + 512);
    __syncthreads();
    short8 bh[4];
    #pragma unroll
    for (int j = 0; j < 4; j++)
      bh[j] = *(const short8*)&Bs[(wn + j * 16 + l15) * 32 + q * 8];
    #pragma unroll
    for (int i = 0; i < 4; i++) {
      short8 ah = *(const short8*)&As[(wm + i * 16 + l15) * 32 + q * 8];
      #pragma unroll
      for (int j = 0; j < 4; j++)
        acc[i][j] = __builtin_amdgcn_mfma_f32_16x16x32_bf16(ah, bh[j], acc[i][j], 0, 0, 0);
    }
    __syncthreads();
  }

  #pragma unroll
  for (int j = 0; j < 4; j++) {
    int col = n0 + wn + j * 16 + l15;
    float bj = bias[col];
    #pragma unroll
    for (int i = 0; i < 4; i++) {
      #pragma unroll
      for (int r = 0; r < 4; r++) {
        int row = m0 + wm + i * 16 + q * 4 + r;
        out[(size_t)row * VOCABN + col] = acc[i][j][r] + bj;
      }
    }
  }
}

// ---------------- host ----------------

extern "C" void kernel_launch(void* const* d_in, const int* in_sizes, int n_in,
                              void* d_out, int out_size, void* d_ws, size_t ws_size,
                              hipStream_t stream) {
  const int*   x   = (const int*)d_in[0];
  const float* emb = (const float*)d_in[1];
  Ptr4 Aw = {{(const float*)d_in[2], (const float*)d_in[6], (const float*)d_in[10], (const float*)d_in[14]}};
  Ptr4 Bw = {{(const float*)d_in[3], (const float*)d_in[7], (const float*)d_in[11], (const float*)d_in[15]}};
  Ptr4 Cw = {{(const float*)d_in[4], (const float*)d_in[8], (const float*)d_in[12], (const float*)d_in[16]}};
  Ptr4 Dw = {{(const float*)d_in[5], (const float*)d_in[9], (const float*)d_in[13], (const float*)d_in[17]}};
  const float* rw1 = (const float*)d_in[18];
  const float* rb1 = (const float*)d_in[19];
  const float* rw2 = (const float*)d_in[20];
  const float* rb2 = (const float*)d_in[21];
  const float* ow  = (const float*)d_in[22];
  const float* ob  = (const float*)d_in[23];
  float* out = (float*)d_out;

  char* wsb = (char*)d_ws;
  size_t off = 0;
  auto alloc = [&](size_t bytes) { size_t o = off; off = (off + bytes + 255) & ~(size_t)255; return o; };

  size_t o_xef  = alloc((size_t)NTOK * DM * 4);
  size_t o_xebf = alloc((size_t)NTOK * DM * 2);
  size_t o_mean = alloc(4 * DM * 4);
  size_t o_w    = alloc(64);
  size_t o_wD   = alloc(4 * DM * 4);
  size_t o_Mh   = alloc((size_t)SZ2 * 2), o_Ml = alloc((size_t)SZ2 * 2);
  size_t o_MTh  = alloc((size_t)SZ2 * 2), o_MTl = alloc((size_t)SZ2 * 2);
  size_t o_P2f  = alloc((size_t)SZ2 * 4);
  size_t o_P2h  = alloc((size_t)SZ2 * 2), o_P2l = alloc((size_t)SZ2 * 2);
  size_t o_P2Th = alloc((size_t)SZ2 * 2), o_P2Tl = alloc((size_t)SZ2 * 2);
  size_t o_P3f  = alloc((size_t)SZ2 * 4);
  size_t o_P4f  = alloc((size_t)SZ2 * 4);
  size_t o_Ph   = alloc((size_t)10 * SZ2 * 2), o_Pl  = alloc((size_t)10 * SZ2 * 2);
  size_t o_PTh  = alloc((size_t)10 * SZ2 * 2), o_PTl = alloc((size_t)10 * SZ2 * 2);
  // zero region: 4 padded X arrays + fp32 op accumulator, contiguous
  size_t o_XAh  = alloc((size_t)XPADE * 2);
  size_t o_XAl  = alloc((size_t)XPADE * 2);
  size_t o_XBh  = alloc((size_t)XPADE * 2);
  size_t o_XBl  = alloc((size_t)XPADE * 2);
  size_t o_opf  = alloc((size_t)NTOK * DM * 4);
  size_t o_Hc   = alloc((size_t)NTOK * DSUM * 2);
  size_t o_op   = alloc((size_t)NTOK * DM * 2);
  size_t o_Bt   = alloc((size_t)DSUM * DM * 2);
  size_t o_Ct   = alloc((size_t)DM * DSUM * 2);
  size_t o_owT  = alloc((size_t)VOCABN * DM * 2);

  auto U16 = [&](size_t o) { return (unsigned short*)(wsb + o); };
  auto F32 = [&](size_t o) { return (float*)(wsb + o); };

  const int dsw[4] = {64, 128, 256, 512};
  const size_t off2[4] = {0, 4096, 20480, 86016};
  const int offc[4] = {0, 64, 192, 448};
  const size_t wxoff[4] = {0, (size_t)XROWS * 64, (size_t)XROWS * 192, (size_t)XROWS * 448};
  const int worder[4] = {3, 2, 1, 0};   // heavy-first for load balance

  auto launchU = [&](GArgs& a) {
    int total = 0;
    for (int i = 0; i < a.nd; i++) {
      a.d[i].boff = total;
      int tm = (a.d[i].M + 127) / 128, tn = (a.d[i].N + 127) / 128;
      a.d[i].tn = tn;
      total += tm * tn;
    }
    gemm_uni<<<total, 256, 0, stream>>>(a);
  };
  auto zd = []() { GDesc d; memset(&d, 0, sizeof(d)); return d; };

  // 1. embed + bf16 copy
  k_embed<<<NTOK, DM, 0, stream>>>(x, emb, F32(o_xef), U16(o_xebf));
  // 2-3. mean, router
  k_mean<<<NB, 1024, 0, stream>>>(F32(o_xef), F32(o_mean));
  k_router<<<1, 256, 0, stream>>>(F32(o_mean), rw1, rb1, rw2, rb2, Dw, F32(o_w), F32(o_wD));
  // 4-5. preps
  k_prep_M<<<SZ2 / 256, 256, 0, stream>>>(Aw, U16(o_Mh), U16(o_Ml), U16(o_MTh), U16(o_MTl));
  k_prep_B<<<DSUM, 256, 0, stream>>>(Bw, U16(o_Bt));
  k_prep_C<<<dim3(4, 256), 256, 0, stream>>>(Cw, U16(o_Ct));
  k_transpose_ow<<<dim3(VOCABN / 64, DM / 64), 256, 0, stream>>>(ow, U16(o_owT));
  // zero padded-X arrays + opf (contiguous)
  {
    long zbytes = (long)4 * XPADE * 2 + (long)NTOK * DM * 4;
    k_zero<<<2048, 256, 0, stream>>>((uint4*)(wsb + o_XAh), zbytes / 16);
  }

  // 6. expm Taylor: P2 = M@M ; P3 = P2@M ; P4 = P2@P2
  {
    GArgs a; a.nd = 4;
    for (int w = 0; w < 4; w++) {
      GDesc d = zd();
      d.Ah = U16(o_Mh) + off2[w]; d.Al = U16(o_Ml) + off2[w];
      d.Bth = U16(o_MTh) + off2[w]; d.Btl = U16(o_MTl) + off2[w];
      d.Cf = F32(o_P2f) + off2[w];
      d.Ch = U16(o_P2h) + off2[w]; d.Cl = U16(o_P2l) + off2[w];
      d.Th = U16(o_P2Th) + off2[w]; d.Tl = U16(o_P2Tl) + off2[w];
      d.M = d.N = d.K = d.lda = d.ldbt = d.ldc = d.ldt = dsw[w];
      d.split = 1;
      a.d[w] = d;
    }
    launchU(a);
  }
  {
    GArgs a; a.nd = 4;
    for (int w = 0; w < 4; w++) {
      GDesc d = zd();
      d.Ah = U16(o_P2h) + off2[w]; d.Al = U16(o_P2l) + off2[w];
      d.Bth = U16(o_MTh) + off2[w]; d.Btl = U16(o_MTl) + off2[w];
      d.Cf = F32(o_P3f) + off2[w];
      d.M = d.N = d.K = d.lda = d.ldbt = d.ldc = dsw[w];
      d.split = 1;
      a.d[w] = d;
    }
    launchU(a);
  }
  {
    GArgs a; a.nd = 4;
    for (int w = 0; w < 4; w++) {
      GDesc d = zd();
      d.Ah = U16(o_P2h) + off2[w]; d.Al = U16(o_P2l) + off2[w];
      d.Bth = U16(o_P2Th) + off2[w]; d.Btl = U16(o_P2Tl) + off2[w];
      d.Cf = F32(o_P4f) + off2[w];
      d.M = d.N = d.K = d.lda = d.ldbt = d.ldc = dsw[w];
      d.split = 1;
      a.d[w] = d;
    }
    launchU(a);
  }
  // 7. combine -> power slot 0 (Ad)
  k_combine<<<SZ2 / 256, 256, 0, stream>>>(Aw, F32(o_P2f), F32(o_P3f), F32(o_P4f),
                                           U16(o_Ph), U16(o_Pl), U16(o_PTh), U16(o_PTl));
  // 8. squaring chain
  for (int j = 1; j < 10; j++) {
    GArgs a; a.nd = 4;
    for (int w = 0; w < 4; w++) {
      size_t so = (size_t)(j - 1) * SZ2 + off2[w];
      size_t do_ = (size_t)j * SZ2 + off2[w];
      GDesc d = zd();
      d.Ah = U16(o_Ph) + so; d.Al = U16(o_Pl) + so;
      d.Bth = U16(o_PTh) + so; d.Btl = U16(o_PTl) + so;
      d.Ch = U16(o_Ph) + do_; d.Cl = U16(o_Pl) + do_;
      d.Th = U16(o_PTh) + do_; d.Tl = U16(o_PTl) + do_;
      d.M = d.N = d.K = d.lda = d.ldbt = d.ldc = d.ldt = dsw[w];
      d.split = 1;
      a.d[w] = d;
    }
    launchU(a);
  }
  // 9. U = xe @ B_w  -> padded X buffer A
  {
    KArgs a; a.nd = 4;
    int total = 0;
    for (int k = 0; k < 4; k++) {
      int w = worder[k];
      KDesc d; memset(&d, 0, sizeof(d));
      d.Ah = U16(o_xebf);
      d.Bth = U16(o_Bt) + (size_t)offc[w] * DM;
      d.Ch = U16(o_XAh) + wxoff[w];
      d.Cl = U16(o_XAl) + wxoff[w];
      d.N = dsw[w]; d.K = DM; d.lda = DM; d.ldbt = DM;
      d.tn = dsw[w] >= 128 ? dsw[w] / 128 : 1;
      d.boff = total; total += 32 * d.tn;
      a.d[k] = d;
    }
    gemm_x<0, 0><<<total, 256, 0, stream>>>(a);
  }
  // 10. Kogge-Stone: 10 rounds
  size_t xin_h = o_XAh, xin_l = o_XAl, xout_h = o_XBh, xout_l = o_XBl;
  for (int j = 0; j < 10; j++) {
    KArgs a; a.nd = 4;
    int total = 0;
    for (int k = 0; k < 4; k++) {
      int w = worder[k];
      KDesc d; memset(&d, 0, sizeof(d));
      d.Ah = U16(xin_h) + wxoff[w];
      d.Al = U16(xin_l) + wxoff[w];
      d.Bth = U16(o_PTh) + (size_t)j * SZ2 + off2[w];
      d.Btl = U16(o_PTl) + (size_t)j * SZ2 + off2[w];
      d.Ch = U16(xout_h) + wxoff[w];
      d.Cl = U16(xout_l) + wxoff[w];
      d.N = dsw[w]; d.K = dsw[w]; d.lda = dsw[w]; d.ldbt = dsw[w];
      d.shift = 1 << j;
      if (j == 9) { d.Hc = U16(o_Hc); d.hcoff = offc[w]; d.wcol = F32(o_w) + w; }
      d.tn = dsw[w] >= 128 ? dsw[w] / 128 : 1;
      d.boff = total; total += 32 * d.tn;
      a.d[k] = d;
    }
    gemm_x<1, 1><<<total, 256, 0, stream>>>(a);
    size_t th = xin_h, tl = xin_l;
    xin_h = xout_h; xin_l = xout_l; xout_h = th; xout_l = tl;
  }
  // 11. opf = H_cat @ C_cat (split-K, atomic), then op = bf16(opf + xe*wD)
  gemm_cct<<<320, 256, 0, stream>>>(U16(o_Hc), U16(o_Ct), F32(o_opf));
  k_finish_op<<<NTOK, DM, 0, stream>>>(F32(o_opf), F32(o_xef), F32(o_wD), U16(o_op));
  // 12. out = op @ ow + ob
  gemm_big<<<8000, 256, 0, stream>>>(U16(o_op), U16(o_owT), ob, out);

  (void)in_sizes; (void)n_in; (void)out_size; (void)ws_size;
}